// Round 21
// baseline (66.589 us; speedup 1.0000x reference)
//
#include <hip/hip_runtime.h>
#include <hip/hip_bf16.h>

#define THRESH 0.05f
constexpr int B_   = 32;
constexpr int CIN  = 128;
constexpr int COUT = 256;
constexpr int HH   = 56;
constexpr int WW   = 56;
constexpr int HWSZ = HH * WW;            // 3136
constexpr int WELEM = COUT * CIN * 9;    // 294912
constexpr int PADW = 58;                 // padded spatial dim
#define XSCALE 32.0f

typedef unsigned short u16;
typedef __attribute__((ext_vector_type(4))) float  f32x4;
typedef __attribute__((ext_vector_type(4))) int    i32x4;

typedef const __attribute__((address_space(1))) void* gas1;
typedef __attribute__((address_space(3))) void* las3;
typedef const __attribute__((address_space(3))) void* lcv;
#define GLOAD16(gsrc, ldst) \
    __builtin_amdgcn_global_load_lds((gas1)(gsrc), (las3)(ldst), 16, 0, 0)

// opaque LDS vector read: compiler cannot sink/fold/remat
#define DSR(dst, base, byteoff) \
    asm volatile("ds_read_b128 %0, %1 offset:%2" : "=v"(dst) : "v"(base), "i"(byteoff))

// ---------------------------------------------------------------------------
// Kernel 1: FUSED  X transpose->i8  +  weight maxabs partials.  (r20 verbatim)
// ---------------------------------------------------------------------------
__global__ __launch_bounds__(256) void x_i8_maxabs(const float* __restrict__ X,
                                                   char* __restrict__ XtP,
                                                   const float* __restrict__ w,
                                                   float* __restrict__ partial) {
    const int tid = threadIdx.x;
    if (blockIdx.x >= 1568) {
        const int pb = blockIdx.x - 1568;
        float m = 0.0f;
        for (int i = pb * 256 + tid; i < WELEM; i += 256 * 256)
            m = fmaxf(m, fabsf(w[i]));
        #pragma unroll
        for (int off = 32; off > 0; off >>= 1) m = fmaxf(m, __shfl_xor(m, off));
        __shared__ float s[4];
        if ((tid & 63) == 0) s[tid >> 6] = m;
        __syncthreads();
        if (tid == 0) partial[pb] = fmaxf(fmaxf(s[0], s[1]), fmaxf(s[2], s[3]));
        return;
    }

    __shared__ char T[64 * 144];               // [64 pos][128 ci pad->144]
    const int b  = blockIdx.x;
    const int n  = b / 49, pt = b - n * 49;
    const int p0 = pt * 64;
    const int ci  = tid >> 1, h2 = tid & 1;

    if (pt == 0) {
        for (int idx = tid; idx < 1824; idx += 256) {
            int c16 = idx & 7, s = idx >> 3;
            int r, c;
            if      (s < 58)  { r = 0;           c = s; }
            else if (s < 116) { r = 57;          c = s - 58; }
            else if (s < 172) { r = s - 116 + 1; c = 0; }
            else              { r = s - 172 + 1; c = 57; }
            size_t site = (size_t)(n * PADW + r) * PADW + c;
            *(i32x4*)(XtP + site * 128 + c16 * 16) = (i32x4){0, 0, 0, 0};
        }
    }

    const float* src = X + ((size_t)(n * CIN + ci)) * HWSZ + p0 + h2 * 32;
    #pragma unroll
    for (int j = 0; j < 8; ++j) {
        f32x4 v = *(const f32x4*)(src + j * 4);
        #pragma unroll
        for (int mth = 0; mth < 4; ++mth) {
            int xi = __float2int_rn(fminf(fmaxf(v[mth] * XSCALE, -127.f), 127.f));
            T[(h2 * 32 + j * 4 + mth) * 144 + ci] = (char)xi;
        }
    }
    __syncthreads();
    #pragma unroll
    for (int k = 0; k < 2; ++k) {
        int idx = tid + k * 256;
        int p = idx >> 3, c16 = idx & 7;
        int gp = p0 + p;
        int h = gp / 56, w2 = gp - h * 56;
        size_t site = (size_t)(n * PADW + 1 + h) * PADW + 1 + w2;
        *(i32x4*)(XtP + site * 128 + c16 * 16) = *(const i32x4*)&T[p * 144 + c16 * 16];
    }
}

// ---------------------------------------------------------------------------
// Kernel 2: reduce + faithful ternary quantize + pack INT8.  (r20 verbatim)
// Apack byte index: ((cc*4 + cot)*64 + row)*576 + tap*64 + swz*16 + e
// ---------------------------------------------------------------------------
__global__ __launch_bounds__(256) void quant_pack(const float* __restrict__ w,
                                                  const float* __restrict__ partial,
                                                  const float* __restrict__ Wn,
                                                  char* __restrict__ Apack) {
    int tid = threadIdx.x;
    float m = partial[tid];
    #pragma unroll
    for (int off = 32; off > 0; off >>= 1) m = fmaxf(m, __shfl_xor(m, off));
    __shared__ float s[4];
    if ((tid & 63) == 0) s[tid >> 6] = m;
    __syncthreads();
    const float mx = fmaxf(fmaxf(s[0], s[1]), fmaxf(s[2], s[3]));
    const float wn = Wn[0];

    int idx = blockIdx.x * 256 + tid;          // ((co*128+ci)*9+tap)
    float nw = w[idx] / mx;
    float q  = (nw > -THRESH && nw <= THRESH) ? 0.0f : nw;
    if (q >  THRESH) q =  1.0f;
    if (q < -THRESH) q = -1.0f;
    if (q == -1.0f)  q = wn;                   // wn == -1.0 exactly

    int tap = idx % 9;
    int r   = idx / 9;
    int ci  = r % CIN;
    int co  = r / CIN;
    int cc  = ci >> 6, lci = ci & 63, kg = lci >> 4, e = lci & 15;
    int cot = co >> 6, row = co & 63;
    int swz = kg ^ ((row >> 1) & 3);
    Apack[(size_t)((cc * 4 + cot) * 64 + row) * 576 + tap * 64 + swz * 16 + e]
        = (char)__float2int_rn(q);
}

// ---------------------------------------------------------------------------
// Kernel 3: implicit-GEMM conv INT8 — WIDENED WAVE TILE (1.33x op/byte):
// wave = 64co x 2 rows -> 12 ds_reads feed 32 MFMA/tap (4x8 frag grid, vs
// 8 reads/16 MFMA before). Block = 7 waves = 64co x 14 rows, 448 thr.
// Grid = 32 img x 4 cot x 4 rowtiles = 512 = EXACTLY 2 rounds.
// LDS: A single-buffered 36.9KB (restaged once at chunk boundary, r12
// pattern) + B double-buffered 2x58KB = 155,648 B, 1 blk/CU.
// Inner pipeline: depth-1 asm lookahead, lgkmcnt(12), setprio,
// mfma_i32_16x16x64_i8. Epilogue: float(acc)/32 (r11-verified store map).
// ---------------------------------------------------------------------------
__global__ __launch_bounds__(448, 2) void conv_mfma(const char* __restrict__ XtP,
                                                    const char* __restrict__ Apack,
                                                    float* __restrict__ out) {
    __shared__ char Alds[36864];       // [64 row][9 tap][64 ci]  (one chunk)
    __shared__ char Xlds[2][59392];    // 2 x [928 site][64 ci]  (16 rows x 58)

    const int tid  = threadIdx.x;
    const int wid  = tid >> 6;         // 0..6
    const int lane = tid & 63;
    const int r16  = lane & 15;
    const int kg   = lane >> 4;

    // XCD swizzle: 512 blocks, 64 per XCD (bijective)
    const int bid = blockIdx.x;
    const int s   = (bid & 7) * 64 + (bid >> 3);
    const int n   = s >> 4;            // image 0..31
    const int rem = s & 15;
    const int by  = rem >> 2;          // 0..3
    const int bx  = rem & 3;           // 0..3
    const int co0 = bx * 64;
    const int h0  = by * 14;

    i32x4 acc[4][8];
    #pragma unroll
    for (int i = 0; i < 4; ++i)
        #pragma unroll
        for (int j = 0; j < 8; ++j) acc[i][j] = (i32x4){0, 0, 0, 0};

    // ---- B-staging source offsets (BYTES, sans cc term): 928 sites x 4 ----
    const int hbase = n * PADW + h0;
    unsigned int bsrc[9];
    #pragma unroll
    for (int i = 0; i < 9; ++i) {
        int p  = i * 448 + tid;
        int pc = (p < 3712) ? p : (p - 3712);   // tail: benign dup (same data+dest)
        int site = pc >> 2, gg = pc & 3;
        int r = site / 58, c = site - r * 58;
        int g2 = gg ^ ((site >> 1) & 3);
        bsrc[i] = (unsigned)(((hbase + r) * PADW + c) * 128 + g2 * 16);
    }
    // B-staging dests (pc-based so tail dups land on same slot)
    int bdst[9];
    #pragma unroll
    for (int i = 0; i < 9; ++i) {
        int p  = i * 448 + (wid * 64);          // wave-uniform base
        bdst[i] = (p < 3712 ? p : p - 3712) * 16;
    }

    // ---- A fragment base (BYTES): XOR term invariant in mf & tap ----
    const int abase0B = r16 * 576 + ((kg ^ ((r16 >> 1) & 3)) << 4);
    // ---- B wave row base (site units) ----
    const int srow = (wid * 2) * 58 + r16;

    // inline swizzled B offset from site
#define BOFFS(SITE) (((SITE) << 6) + ((kg ^ (((SITE) >> 1) & 3)) << 4))
    // per-(tap,row) site: srow + (t/3+r)*58 + (t%3), t and r compile-time
#define BSITE(T, R) (srow + (((T) / 3) + (R)) * 58 + ((T) % 3))

    // B read burst for tap TT into set SS (8 frags, 2 rows x 4 nf)
#define BRD(SS, TT)                                                           \
    {                                                                         \
        int s0_ = BSITE((TT), 0), s1_ = BSITE((TT), 1);                       \
        lcv xb0_ = (lcv)(XbG + BOFFS(s0_));                                   \
        lcv xb1_ = (lcv)(XbG + BOFFS(s1_));                                   \
        DSR(bf[SS][0], xb0_, 0);    DSR(bf[SS][1], xb0_, 1024);               \
        DSR(bf[SS][2], xb0_, 2048); DSR(bf[SS][3], xb0_, 3072);               \
        DSR(bf[SS][4], xb1_, 0);    DSR(bf[SS][5], xb1_, 1024);               \
        DSR(bf[SS][6], xb1_, 2048); DSR(bf[SS][7], xb1_, 3072);               \
    }
#define ARD(SS, TT)                                                           \
    {                                                                         \
        DSR(af[SS][0], Ab, 0 * 9216 + ((TT)) * 64);                           \
        DSR(af[SS][1], Ab, 1 * 9216 + ((TT)) * 64);                           \
        DSR(af[SS][2], Ab, 2 * 9216 + ((TT)) * 64);                           \
        DSR(af[SS][3], Ab, 3 * 9216 + ((TT)) * 64);                           \
    }
#define STAGE_A(CC)                                                           \
    {                                                                         \
        const char* asrc_ = Apack + (size_t)((CC) * 4 + bx) * 36864;          \
        _Pragma("unroll")                                                     \
        for (int i = 0; i < 5; ++i)                                           \
            GLOAD16(asrc_ + (size_t)(i * 448 + tid) * 16,                     \
                    &Alds[(i * 448 + wid * 64) * 16]);                        \
        if (wid == 0)                                                         \
            GLOAD16(asrc_ + (size_t)(2240 + lane) * 16, &Alds[2240 * 16]);    \
    }
#define STAGE_B(CC, BUF)                                                      \
    {                                                                         \
        _Pragma("unroll")                                                     \
        for (int i = 0; i < 9; ++i)                                           \
            GLOAD16(XtP + (size_t)bsrc[i] + (CC) * 64, &Xlds[BUF][bdst[i]]);  \
    }

    // ---- prologue: stage A(c0) + B(c0), drain, barrier ----
    STAGE_A(0)
    STAGE_B(0, 0)
    asm volatile("s_waitcnt vmcnt(0)" ::: "memory");
    __builtin_amdgcn_s_barrier();
    __builtin_amdgcn_sched_barrier(0);

    lcv Ab = (lcv)(&Alds[0] + abase0B);
    i32x4 af[2][4], bf[2][8];

    #pragma unroll
    for (int cc = 0; cc < 2; ++cc) {
        const char* XbG = &Xlds[cc][0];

        // issue B prefetch for chunk 1 during chunk 0
        if (cc == 0) STAGE_B(1, 1)

        ARD(0, 0) BRD(0, 0)          // preload tap 0
        __builtin_amdgcn_sched_barrier(0);

        #pragma unroll
        for (int t = 0; t < 9; ++t) {
            const int c  = t & 1;
            const int nx = c ^ 1;
            if (t < 8) {
                ARD(nx, (t + 1)) BRD(nx, (t + 1))
                asm volatile("s_waitcnt lgkmcnt(12)" ::: "memory");
            } else {
                asm volatile("s_waitcnt lgkmcnt(0)" ::: "memory");
            }
            __builtin_amdgcn_sched_barrier(0);   // rule 18: MFMAs stay below wait
            __builtin_amdgcn_s_setprio(1);
            #pragma unroll
            for (int mf = 0; mf < 4; ++mf)
                #pragma unroll
                for (int nf = 0; nf < 8; ++nf)
                    acc[mf][nf] = __builtin_amdgcn_mfma_i32_16x16x64_i8(
                        af[c][mf], bf[c][nf], acc[mf][nf], 0, 0, 0);
            __builtin_amdgcn_s_setprio(0);
            __builtin_amdgcn_sched_barrier(0);   // keep next prefetch below MFMAs
        }

        // ---- chunk boundary: restage A (single-buffered), drain, resync ----
        if (cc == 0) {
            __builtin_amdgcn_s_barrier();        // all waves done reading Alds(c0)
            STAGE_A(1)
            asm volatile("s_waitcnt vmcnt(0)" ::: "memory");  // A(c1)+B(c1) done
            __builtin_amdgcn_s_barrier();
            __builtin_amdgcn_sched_barrier(0);
        }
    }
#undef STAGE_B
#undef STAGE_A
#undef ARD
#undef BRD
#undef BSITE
#undef BOFFS

    // ---- store: col=(nf&3)*16+r16, h=h0+wid*2+(nf>>2), co=mf*16+kg*4+j ----
    #pragma unroll
    for (int mf = 0; mf < 4; ++mf)
        #pragma unroll
        for (int nf = 0; nf < 8; ++nf) {
            int col = (nf & 3) * 16 + r16;
            if (col < WW) {
                int h = h0 + wid * 2 + (nf >> 2);
                float* op = out + ((size_t)(n * COUT + co0 + mf * 16 + kg * 4)) * HWSZ
                            + h * WW + col;
                #pragma unroll
                for (int j = 0; j < 4; ++j)
                    op[(size_t)j * HWSZ] = (float)acc[mf][nf][j] * (1.0f / XSCALE);
            }
        }
}

// ---------------------------------------------------------------------------
// Launch
// ---------------------------------------------------------------------------
extern "C" void kernel_launch(void* const* d_in, const int* in_sizes, int n_in,
                              void* d_out, int out_size, void* d_ws, size_t ws_size,
                              hipStream_t stream) {
    const float* X      = (const float*)d_in[0];
    const float* weight = (const float*)d_in[1];
    // Wp (d_in[2]) never enters the forward (faithful to source)
    const float* Wn     = (const float*)d_in[3];
    float* out = (float*)d_out;

    float* ws_partial = (float*)d_ws;                        // 256 f32
    char*  ws_apack   = (char*)d_ws + 4096;                  // 294912 B
    char*  ws_xtp     = (char*)d_ws + (1 << 20);             // 32*3364*128 B (~13.8 MB)

    x_i8_maxabs<<<1568 + 256, 256, 0, stream>>>(X, ws_xtp, weight, ws_partial);
    quant_pack<<<WELEM / 256, 256, 0, stream>>>(weight, ws_partial, Wn, ws_apack);

    conv_mfma<<<512, 448, 0, stream>>>(ws_xtp, ws_apack, out);
}

// Round 22
// 60.114 us; speedup vs baseline: 1.1077x; 1.1077x over previous
//
#include <hip/hip_runtime.h>
#include <hip/hip_bf16.h>

#define THRESH 0.05f
constexpr int B_   = 32;
constexpr int CIN  = 128;
constexpr int COUT = 256;
constexpr int HH   = 56;
constexpr int WW   = 56;
constexpr int HWSZ = HH * WW;            // 3136
constexpr int WELEM = COUT * CIN * 9;    // 294912
constexpr int PADW = 58;                 // padded spatial dim
#define XSCALE 32.0f

typedef unsigned short u16;
typedef __attribute__((ext_vector_type(4))) float  f32x4;
typedef __attribute__((ext_vector_type(4))) int    i32x4;

typedef const __attribute__((address_space(1))) void* gas1;
typedef __attribute__((address_space(3))) void* las3;
typedef const __attribute__((address_space(3))) void* lcv;
#define GLOAD16(gsrc, ldst) \
    __builtin_amdgcn_global_load_lds((gas1)(gsrc), (las3)(ldst), 16, 0, 0)

// opaque LDS vector read: compiler cannot sink/fold/remat
#define DSR(dst, base, byteoff) \
    asm volatile("ds_read_b128 %0, %1 offset:%2" : "=v"(dst) : "v"(base), "i"(byteoff))

// ---------------------------------------------------------------------------
// Kernel 1: FUSED  X transpose->i8  +  weight maxabs partials.
// ---------------------------------------------------------------------------
__global__ __launch_bounds__(256) void x_i8_maxabs(const float* __restrict__ X,
                                                   char* __restrict__ XtP,
                                                   const float* __restrict__ w,
                                                   float* __restrict__ partial) {
    const int tid = threadIdx.x;
    if (blockIdx.x >= 1568) {
        const int pb = blockIdx.x - 1568;
        float m = 0.0f;
        for (int i = pb * 256 + tid; i < WELEM; i += 256 * 256)
            m = fmaxf(m, fabsf(w[i]));
        #pragma unroll
        for (int off = 32; off > 0; off >>= 1) m = fmaxf(m, __shfl_xor(m, off));
        __shared__ float s[4];
        if ((tid & 63) == 0) s[tid >> 6] = m;
        __syncthreads();
        if (tid == 0) partial[pb] = fmaxf(fmaxf(s[0], s[1]), fmaxf(s[2], s[3]));
        return;
    }

    __shared__ char T[64 * 144];               // [64 pos][128 ci pad->144]
    const int b  = blockIdx.x;
    const int n  = b / 49, pt = b - n * 49;
    const int p0 = pt * 64;
    const int ci  = tid >> 1, h2 = tid & 1;

    if (pt == 0) {
        for (int idx = tid; idx < 1824; idx += 256) {
            int c16 = idx & 7, s = idx >> 3;
            int r, c;
            if      (s < 58)  { r = 0;           c = s; }
            else if (s < 116) { r = 57;          c = s - 58; }
            else if (s < 172) { r = s - 116 + 1; c = 0; }
            else              { r = s - 172 + 1; c = 57; }
            size_t site = (size_t)(n * PADW + r) * PADW + c;
            *(i32x4*)(XtP + site * 128 + c16 * 16) = (i32x4){0, 0, 0, 0};
        }
    }

    const float* src = X + ((size_t)(n * CIN + ci)) * HWSZ + p0 + h2 * 32;
    #pragma unroll
    for (int j = 0; j < 8; ++j) {
        f32x4 v = *(const f32x4*)(src + j * 4);
        #pragma unroll
        for (int mth = 0; mth < 4; ++mth) {
            int xi = __float2int_rn(fminf(fmaxf(v[mth] * XSCALE, -127.f), 127.f));
            T[(h2 * 32 + j * 4 + mth) * 144 + ci] = (char)xi;
        }
    }
    __syncthreads();
    #pragma unroll
    for (int k = 0; k < 2; ++k) {
        int idx = tid + k * 256;
        int p = idx >> 3, c16 = idx & 7;
        int gp = p0 + p;
        int h = gp / 56, w2 = gp - h * 56;
        size_t site = (size_t)(n * PADW + 1 + h) * PADW + 1 + w2;
        *(i32x4*)(XtP + site * 128 + c16 * 16) = *(const i32x4*)&T[p * 144 + c16 * 16];
    }
}

// ---------------------------------------------------------------------------
// Kernel 2: reduce + faithful ternary quantize + pack INT8 (PERMUTED layout)
// Apack byte index: ((cc*4 + cot)*64 + row)*576 + tap*64 + swz*16 + e
// ---------------------------------------------------------------------------
__global__ __launch_bounds__(256) void quant_pack(const float* __restrict__ w,
                                                  const float* __restrict__ partial,
                                                  const float* __restrict__ Wn,
                                                  char* __restrict__ Apack) {
    int tid = threadIdx.x;
    float m = partial[tid];
    #pragma unroll
    for (int off = 32; off > 0; off >>= 1) m = fmaxf(m, __shfl_xor(m, off));
    __shared__ float s[4];
    if ((tid & 63) == 0) s[tid >> 6] = m;
    __syncthreads();
    const float mx = fmaxf(fmaxf(s[0], s[1]), fmaxf(s[2], s[3]));
    const float wn = Wn[0];

    int idx = blockIdx.x * 256 + tid;          // ((co*128+ci)*9+tap)
    float nw = w[idx] / mx;
    float q  = (nw > -THRESH && nw <= THRESH) ? 0.0f : nw;
    if (q >  THRESH) q =  1.0f;
    if (q < -THRESH) q = -1.0f;
    if (q == -1.0f)  q = wn;                   // wn == -1.0 exactly

    int tap = idx % 9;
    int r   = idx / 9;
    int ci  = r % CIN;
    int co  = r / CIN;
    int cc  = ci >> 6, lci = ci & 63, kg = lci >> 4, e = lci & 15;
    int cot = co >> 6, row = co & 63;
    int swz = kg ^ ((row >> 1) & 3);
    Apack[(size_t)((cc * 4 + cot) * 64 + row) * 576 + tap * 64 + swz * 16 + e]
        = (char)__float2int_rn(q);
}

// ---------------------------------------------------------------------------
// Kernel 3: implicit-GEMM conv INT8 — measured-best configuration (r20):
// 64co x 7rows, 448 thr / 7 waves, grid = 1024 = exactly 4 rounds of 256 CUs,
// double-buffered A+B LDS (147.5 KB, 1 blk/CU; 2 blk/CU thrashes L2 store-
// side, measured r6+r18), one barrier per chunk, 2 chunks of 64 ci, depth-1
// asm lookahead, lgkmcnt(8), setprio, mfma_i32_16x16x64_i8. Epilogue /32.
// Wider per-wave tiles exceed the 256-VGPR cap (r21, -10%); 6 scheduling
// variants (r4-r16) could not overlap LDS-read and MFMA pipes beyond this.
// ---------------------------------------------------------------------------
__global__ __launch_bounds__(448, 2) void conv_mfma(const char* __restrict__ XtP,
                                                    const char* __restrict__ Apack,
                                                    float* __restrict__ out) {
    __shared__ char Alds[2][36864];    // 2 x [64 row][9 tap][64 ci]
    __shared__ char Xlds[2][36864];    // 2 x [522 site][64 ci] (padded to 2304 slots)

    const int tid  = threadIdx.x;
    const int wid  = tid >> 6;         // 0..6
    const int lane = tid & 63;
    const int r16  = lane & 15;
    const int kg   = lane >> 4;

    // XCD swizzle: 1024 blocks, 128 per XCD (bijective)
    const int bid = blockIdx.x;
    const int s   = (bid & 7) * 128 + (bid >> 3);
    const int n   = s >> 5;            // image 0..31
    const int rem = s & 31;
    const int by  = rem >> 2;          // 0..7
    const int bx  = rem & 3;           // 0..3
    const int co0 = bx * 64;
    const int h0  = by * 7;

    i32x4 acc[4][4];
    #pragma unroll
    for (int i = 0; i < 4; ++i)
        #pragma unroll
        for (int j = 0; j < 4; ++j) acc[i][j] = (i32x4){0, 0, 0, 0};

    // ---- B-staging source offsets (BYTES, sans cc term): 522 sites x 4 ----
    const int hbase = n * PADW + h0;
    unsigned int bsrc[5];
    #pragma unroll
    for (int i = 0; i < 5; ++i) {
        int p  = i * 448 + tid;
        int pc = (p < 2088) ? p : (p - 2088);       // clamp tail (dest goes to pad)
        int site = pc >> 2, gg = pc & 3;
        int r = site / 58, c = site - r * 58;
        int g2 = gg ^ ((site >> 1) & 3);
        bsrc[i] = (unsigned)(((hbase + r) * PADW + c) * 128 + g2 * 16);
    }

    // ---- A fragment base (BYTES): XOR term invariant in mf & tap ----
    const int abase0B = r16 * 576 + ((kg ^ ((r16 >> 1) & 3)) << 4);

    // ---- B per-tap offsets (BYTES): XOR term invariant in nf ----
    int otapB[9];
    #pragma unroll
    for (int t = 0; t < 9; ++t) {
        int base_t = (wid + t / 3) * 58 + r16 + (t % 3);
        otapB[t] = base_t * 64 + ((kg ^ ((base_t >> 1) & 3)) << 4);
    }

    // ---- prologue: stage chunk 0 into buffer 0, full drain ----
    {
        const char* asrc = Apack + (size_t)bx * 36864;
        #pragma unroll
        for (int i = 0; i < 5; ++i)       // 5*448 = 2240 of 2304 A chunks
            GLOAD16(asrc + (size_t)(i * 448 + tid) * 16,
                    &Alds[0][(i * 448 + wid * 64) * 16]);
        if (wid == 0)                     // tail 64 chunks, wave-uniform branch
            GLOAD16(asrc + (size_t)(2240 + lane) * 16, &Alds[0][2240 * 16]);
        #pragma unroll
        for (int i = 0; i < 5; ++i)       // 2240 >= 2088 B chunks (tail -> pad)
            GLOAD16(XtP + (size_t)bsrc[i], &Xlds[0][(i * 448 + wid * 64) * 16]);
        asm volatile("s_waitcnt vmcnt(0)" ::: "memory");
        __builtin_amdgcn_s_barrier();
        __builtin_amdgcn_sched_barrier(0);
    }

    #pragma unroll
    for (int cc = 0; cc < 2; ++cc) {
        const int cur = cc & 1;
        const int nxt = cur ^ 1;

        // ---- issue ALL staging for chunk cc+1 (vmem pipe, independent) ----
        if (cc < 1) {
            const char* asrc_n = Apack + (size_t)((cc + 1) * 4 + bx) * 36864;
            #pragma unroll
            for (int i = 0; i < 5; ++i)
                GLOAD16(asrc_n + (size_t)(i * 448 + tid) * 16,
                        &Alds[nxt][(i * 448 + wid * 64) * 16]);
            if (wid == 0)
                GLOAD16(asrc_n + (size_t)(2240 + lane) * 16, &Alds[nxt][2240 * 16]);
            #pragma unroll
            for (int i = 0; i < 5; ++i)
                GLOAD16(XtP + (size_t)bsrc[i] + 64,
                        &Xlds[nxt][(i * 448 + wid * 64) * 16]);
        }

        // ---- asm ds_read pipelined 9-tap stream, depth 1 ----
        lcv Ab = (lcv)(&Alds[cur][0] + abase0B);
        const char* XbG = &Xlds[cur][0];

        i32x4 af[2][4], bf[2][4];
        {   // preload tap 0
            lcv xb = (lcv)(XbG + otapB[0]);
            DSR(af[0][0], Ab, 0 * 9216);
            DSR(af[0][1], Ab, 1 * 9216);
            DSR(af[0][2], Ab, 2 * 9216);
            DSR(af[0][3], Ab, 3 * 9216);
            DSR(bf[0][0], xb, 0);
            DSR(bf[0][1], xb, 1024);
            DSR(bf[0][2], xb, 2048);
            DSR(bf[0][3], xb, 3072);
        }

        #pragma unroll
        for (int t = 0; t < 9; ++t) {
            const int c  = t & 1;
            const int nx = c ^ 1;
            if (t < 8) {
                lcv xb = (lcv)(XbG + otapB[t + 1]);
                DSR(af[nx][0], Ab, 0 * 9216 + (t + 1) * 64);
                DSR(af[nx][1], Ab, 1 * 9216 + (t + 1) * 64);
                DSR(af[nx][2], Ab, 2 * 9216 + (t + 1) * 64);
                DSR(af[nx][3], Ab, 3 * 9216 + (t + 1) * 64);
                DSR(bf[nx][0], xb, 0);
                DSR(bf[nx][1], xb, 1024);
                DSR(bf[nx][2], xb, 2048);
                DSR(bf[nx][3], xb, 3072);
                asm volatile("s_waitcnt lgkmcnt(8)" ::: "memory");
            } else {
                asm volatile("s_waitcnt lgkmcnt(0)" ::: "memory");
            }
            __builtin_amdgcn_sched_barrier(0);   // rule 18: MFMAs stay below wait
            __builtin_amdgcn_s_setprio(1);
            #pragma unroll
            for (int mf = 0; mf < 4; ++mf)
                #pragma unroll
                for (int nf = 0; nf < 4; ++nf)
                    acc[mf][nf] = __builtin_amdgcn_mfma_i32_16x16x64_i8(
                        af[c][mf], bf[c][nf], acc[mf][nf], 0, 0, 0);
            __builtin_amdgcn_s_setprio(0);
            __builtin_amdgcn_sched_barrier(0);   // keep next prefetch below MFMAs
        }

        // ---- chunk boundary: drain staging, one barrier, flip ----
        if (cc < 1) {
            asm volatile("s_waitcnt vmcnt(0)" ::: "memory");
            __builtin_amdgcn_s_barrier();
            __builtin_amdgcn_sched_barrier(0);
        }
    }

    // ---- store: D col = r16 (spatial), row = kg*4+j (co); out = acc/32 ----
    const int h = h0 + wid;
    float* obase = out + ((size_t)(n * COUT + co0)) * HWSZ + h * WW;
    #pragma unroll
    for (int mf = 0; mf < 4; ++mf)
        #pragma unroll
        for (int nf = 0; nf < 4; ++nf) {
            int col = nf * 16 + r16;
            if (col < WW) {
                #pragma unroll
                for (int j = 0; j < 4; ++j) {
                    int co = mf * 16 + kg * 4 + j;
                    obase[(size_t)co * HWSZ + col] = (float)acc[mf][nf][j] * (1.0f / XSCALE);
                }
            }
        }
}

// ---------------------------------------------------------------------------
// Launch
// ---------------------------------------------------------------------------
extern "C" void kernel_launch(void* const* d_in, const int* in_sizes, int n_in,
                              void* d_out, int out_size, void* d_ws, size_t ws_size,
                              hipStream_t stream) {
    const float* X      = (const float*)d_in[0];
    const float* weight = (const float*)d_in[1];
    // Wp (d_in[2]) never enters the forward (faithful to source)
    const float* Wn     = (const float*)d_in[3];
    float* out = (float*)d_out;

    float* ws_partial = (float*)d_ws;                        // 256 f32
    char*  ws_apack   = (char*)d_ws + 4096;                  // 294912 B
    char*  ws_xtp     = (char*)d_ws + (1 << 20);             // 32*3364*128 B (~13.8 MB)

    x_i8_maxabs<<<1568 + 256, 256, 0, stream>>>(X, ws_xtp, weight, ws_partial);
    quant_pack<<<WELEM / 256, 256, 0, stream>>>(weight, ws_partial, Wn, ws_apack);

    conv_mfma<<<1024, 448, 0, stream>>>(ws_xtp, ws_apack, out);
}